// Round 12
// baseline (272.884 us; speedup 1.0000x reference)
//
#include <hip/hip_runtime.h>
#include <stdint.h>
#include <utility>

// ---------------------------------------------------------------------------
// SparseResUQueryNet: bitmap+rank sparse conv -> time max-pool -> sparse conv
//
// Round-20 = round-19 (verified 256.4us) + fused 96-key probe entries:
//   - {u64 bm_lo, u32 bm_hi, u32 rank} = 16B covers 96 keys; ONE uint4 load
//     per tap replaces the parallel bm+rank pair. Probe requests 54->27 per
//     point in BOTH hot kernels; chain depth unchanged (1 round-trip);
//     footprint SHRINKS (hist 50.3->44.7MB, pool 6->5.6MB — not r6's 8.4MB
//     fused mistake). Entry address is pure VALU (magic div-3; r18 lesson).
//   - scan restructured to 3 words/thread (= exactly 2 entries); the
//     wave-parallel decoupled lookback is UNCHANGED. Entry writes cost
//     ~+5us (50MB vs 19MB) — the bet is probes buy more.
// Kept: kp key-packing (r19), assume hints (r16), ds_swizzle k-broadcast
// (r15), XCD-chunked swizzle in bb_pool (r13), float2 stores, memset cut,
// 27-lane parallel probe, half-wave per point, VGPR<=32.
// Lessons ledger: wave shape frozen (r9/r10/r12); probe addr pure VALU and
// chain depth 1 (r9/r18); footprint <= split (r6).
// ---------------------------------------------------------------------------

#define TPB 256
#define GB_H2 5462          // hist scan blocks: ceil(2^22 words / (256*3))
#define GB_P2 683           // pool scan blocks: ceil(2^19 words / (256*3))
#define NBLK_SCAN (GB_H2 + GB_P2)
typedef unsigned long long u64;
typedef unsigned int u32;
typedef unsigned short u16;

#define FLAG_AGG (1ull << 62)
#define FLAG_PRE (2ull << 62)
#define FLAG_MSK (3ull << 62)

// exact u32 divide by 3 (x < 2^31): classic magic multiply
__device__ __forceinline__ u32 div3(u32 x) {
    return (u32)(((u64)x * 0xAAAAAAABull) >> 33);
}

// f32 -> RNE bf16 -> monotone u16 (order-preserving; 0 is below all reals)
__device__ __forceinline__ u32 trans16(float x) {
    u32 b = __float_as_uint(x);
    u32 bf = (b + 0x7FFFu + ((b >> 16) & 1u)) >> 16;
    return ((bf & 0x8000u) ? (~bf) : (bf | 0x8000u)) & 0xFFFFu;
}
__device__ __forceinline__ float detrans16(u32 u) {
    u32 orig = (u & 0x8000u) ? (u & 0x7FFFu) : ((~u) & 0xFFFFu);
    return __uint_as_float(orig << 16);
}

// broadcast lane K (within each 32-lane half) of pv, FMA against W[K*32] ----
template <int... Ks>
__device__ __forceinline__ void kfma(float pv, const float* __restrict__ W,
                                     float& acc,
                                     std::integer_sequence<int, Ks...>) {
    ((acc = fmaf(__uint_as_float((u32)__builtin_amdgcn_ds_swizzle(
                     (int)__float_as_uint(pv), (Ks << 5))),
                 W[Ks * 32], acc)),
     ...);
}

// K1: set existence bits; second pool contributor marks multi; pack keys -----
__global__ void build_bitmaps_kernel(const int4* __restrict__ hc,
                                     const int* __restrict__ hb,
                                     int n,
                                     u64* __restrict__ hist_bm,
                                     u64* __restrict__ pool_bm,
                                     u64* __restrict__ multi_bm,
                                     int2* __restrict__ kp) {
    int j = blockIdx.x * blockDim.x + threadIdx.x;
    if (j >= n) return;
    int4 c = hc[j];                                   // (t,x,y,z)
    int key = ((c.x * 256 + c.y) * 256 + c.z) * 256 + c.w;
    atomicOr(&hist_bm[key >> 6], 1ull << (key & 63));
    int pk = ((hb[j] * 256 + c.y) * 256 + c.z) * 256 + c.w;
    kp[j] = make_int2(key, pk);                       // keys for bb_pool
    u64 bit = 1ull << (pk & 63);
    u64 old = atomicOr(&pool_bm[pk >> 6], bit);
    if (old & bit) atomicOr(&multi_bm[pk >> 6], bit); // >=2 contributors
}

// single-pass scan (3 words = 2 entries per thread) + wave-parallel lookback.
// Writes fused 96-key entries {bm_lo, bm_hi32, rank}; pool branch also
// zeroes the CAS-max pooled rows (fused zero_multi) -------------------------
__global__ void scan_fused_kernel(const u64* __restrict__ hist_bm,
                                  const u64* __restrict__ pool_bm,
                                  uint4* __restrict__ hist_ent,
                                  uint4* __restrict__ pool_ent,
                                  const u64* __restrict__ multi_bm,
                                  u32* __restrict__ pooled,
                                  u64* __restrict__ st) {  // [NBLK_SCAN] zeroed
    __shared__ u32 s[TPB];
    __shared__ u32 sbase;
    int t = threadIdx.x;
    bool isPool = blockIdx.x >= GB_H2;
    const u64* bm = isPool ? pool_bm : hist_bm;
    uint4* ent = isPool ? pool_ent : hist_ent;
    int NW = isPool ? (1 << 19) : (1 << 22);
    int blk = isPool ? (blockIdx.x - GB_H2) : blockIdx.x;
    size_t w0i = ((size_t)blk * TPB + t) * 3;
    u64 w0 = (w0i     < (size_t)NW) ? bm[w0i]     : 0ull;  // guarded tail
    u64 w1 = (w0i + 1 < (size_t)NW) ? bm[w0i + 1] : 0ull;
    u64 w2 = (w0i + 2 < (size_t)NW) ? bm[w0i + 2] : 0ull;
    u32 pc0 = (u32)__popcll(w0), pc1 = (u32)__popcll(w1), pc2 = (u32)__popcll(w2);
    u32 pcT = pc0 + pc1 + pc2;
    s[t] = pcT; __syncthreads();
    for (int off = 1; off < TPB; off <<= 1) {          // inclusive Hillis-Steele
        u32 x = (t >= off) ? s[t - off] : 0;
        __syncthreads();
        s[t] += x;
        __syncthreads();
    }
    u32 wave_excl = s[t] - pcT;                        // block-local exclusive
    u32 blocksum = s[TPB - 1];                         // block aggregate

    int segStart = isPool ? GB_H2 : 0;
    if (t < 64) {                                      // first wave does lookback
        if (blockIdx.x == segStart) {                  // segment head
            if (t == 0) {
                atomicExch(&st[blockIdx.x], FLAG_PRE | (u64)blocksum);
                sbase = 0;
            }
        } else {
            if (t == 0) atomicExch(&st[blockIdx.x], FLAG_AGG | (u64)blocksum);
            u64 run = 0;
            int end = blockIdx.x;                      // window (end-64, end]
            while (true) {
                int i = end - 1 - t;                   // lane 0 = closest pred
                u64 v = (i >= segStart) ? atomicAdd(&st[i], 0ull)
                                        : FLAG_AGG;    // synthetic AGG(0)
                u64 fl = v & FLAG_MSK;
                u64 pre_mask   = __ballot(fl == FLAG_PRE);
                u64 unpub_mask = __ballot(fl == 0ull);
                int first_pre   = pre_mask   ? (__ffsll((long long)pre_mask) - 1)   : 64;
                int first_unpub = unpub_mask ? (__ffsll((long long)unpub_mask) - 1) : 64;
                if (first_pre < first_unpub) {         // consumable prefix found
                    u32 contrib = (t <= first_pre) ? (u32)(v & 0xFFFFFFFFull) : 0u;
#pragma unroll
                    for (int off = 1; off < 64; off <<= 1)
                        contrib += (u32)__shfl_xor((int)contrib, off);
                    run += contrib;
                    break;
                } else if (first_unpub == 64) {        // all AGG: consume window
                    u32 contrib = (u32)(v & 0xFFFFFFFFull);
#pragma unroll
                    for (int off = 1; off < 64; off <<= 1)
                        contrib += (u32)__shfl_xor((int)contrib, off);
                    run += contrib;
                    end -= 64;
                }                                      // else: re-poll window
            }
            if (t == 0) {
                atomicExch(&st[blockIdx.x], FLAG_PRE | (run + (u64)blocksum));
                sbase = (u32)run;
            }
        }
    }
    __syncthreads();

    u32 run = sbase + wave_excl;                       // rank at key w0i*64
    // entry 0: keys [base, base+96): bm = w0 | lo32(w1)
    u32 lo1 = (u32)w1;
    u32 e0 = ((u32)blk * TPB + (u32)t) * 2;
    ent[e0] = make_uint4((u32)w0, (u32)(w0 >> 32), lo1, run);
    // entry 1: keys [base+96, base+192): bm = hi32(w1) | w2
    u64 a1 = (w1 >> 32) | (w2 << 32);
    u32 r1 = run + pc0 + (u32)__popc(lo1);
    ent[e0 + 1] = make_uint4((u32)a1, (u32)(a1 >> 32), (u32)(w2 >> 32), r1);

    if (isPool) {                                      // fused zero_multi
        u32 rw0 = run, rw1 = run + pc0, rw2 = run + pc0 + pc1;
        u64 wv[3] = {w0, w1, w2};
        u32 rv[3] = {rw0, rw1, rw2};
#pragma unroll
        for (int i = 0; i < 3; i++) {
            if (w0i + i < (size_t)NW) {
                u64 mw = multi_bm[w0i + i];
                if (mw) {
                    u64 pw = wv[i];
                    while (mw) {
                        int b = __ffsll((long long)mw) - 1;
                        mw &= mw - 1;
                        u32 slot = rv[i] + (u32)__popcll(pw & ((1ull << b) - 1ull));
                        u32* row = pooled + (size_t)slot * 16;
#pragma unroll
                        for (int q2 = 0; q2 < 16; q2++) row[q2] = 0u;
                    }
                }
            }
        }
    }
}

// K2: half-wave per voxel: 27-tap conv (1->32) + packed pooled write --------
__global__ __launch_bounds__(TPB, 8)
void bb_pool_kernel(const int2* __restrict__ kp,      // packed (key, pk)
                    const float* __restrict__ hf,
                    const float* __restrict__ Wbb,   // [27*32]
                    int n,
                    const uint4* __restrict__ hist_ent,
                    const uint4* __restrict__ pool_ent,
                    const u64* __restrict__ multi_bm,
                    u32* __restrict__ pooled) {
    // XCD-chunked bijective swizzle (r13, verified): contiguous key range per
    // XCD so its private L2 holds 1/8 of the hist entries.
    int nwg = gridDim.x;
    int q = nwg >> 3, r = nwg & 7;
    int xcd = blockIdx.x & 7, idx = blockIdx.x >> 3;
    int swz = (xcd < r ? xcd * (q + 1) : r * (q + 1) + (xcd - r) * q) + idx;

    int p = (swz * TPB + threadIdx.x) >> 5;            // voxel index
    if (p >= n) return;
    int lane = threadIdx.x & 63;
    int hb32 = lane & 32;                              // half base within wave
    int f = lane & 31;                                 // feature / tap lane

    int2 k2 = kp[p];                                   // one 8B broadcast load
    int key = k2.x, pk = k2.y;
    __builtin_assume(key >= 65793 && key < (1 << 28)); // t<16, x/y/z in [1,251)
    __builtin_assume(pk >= 65793 && pk < (1 << 25));   // b<2

    // pool-side loads issued early (independent of probe chain)
    u32 ep = div3((u32)pk >> 5);
    u32 offp = (u32)pk - ep * 96u;
    uint4 PE = pool_ent[ep];                           // 16B: bm96 + rank
    u64 mword = multi_bm[pk >> 6];

    float fv = 0.f;
    bool hit = false;
    if (f < 27) {
        int t1 = f / 9, rem = f - t1 * 9, t2 = rem / 3, t3 = rem - t2 * 3;
        int nk = key + (t1 - 1) * 65536 + (t2 - 1) * 256 + (t3 - 1);
        __builtin_assume(nk >= 0 && nk < (1 << 28));
        u32 e = div3((u32)nk >> 5);                    // pure-VALU addr (r18)
        u32 off = (u32)nk - e * 96u;
        uint4 E = hist_ent[e];                         // ONE 16B scattered load
        u64 a = ((u64)E.y << 32) | E.x;
        bool lo = off < 64u;
        u32 offh = (off - 64u) & 31u;
        u32 bitv = lo ? (u32)((a >> (off & 63u)) & 1ull)
                      : ((E.z >> offh) & 1u);
        if (bitv) {
            u32 sub = lo ? (u32)__popcll(a & ((1ull << (off & 63u)) - 1ull))
                         : (u32)__popcll(a) + (u32)__popc(E.z & ((1u << offh) - 1u));
            u32 r2 = E.w + sub;
            __builtin_assume(r2 < (1u << 20));         // rank < n < 2^20
            fv = hf[r2];                               // rank == row index j
            hit = true;
        }
    }
    unsigned long long bal = __ballot(hit);
    u32 mymask = (u32)(bal >> hb32);                   // this half's hit taps

    float acc = 0.f;
    while (mymask) {
        int b = __ffs(mymask) - 1;
        mymask &= mymask - 1;
        float fb = __shfl(fv, hb32 + b);               // broadcast neighbor feat
        acc = fmaf(fb, Wbb[b * 32 + f], acc);          // L1-hot 3.4KB table
    }

    // output slot from the early pool entry
    u64 pa = ((u64)PE.y << 32) | PE.x;
    bool plo = offp < 64u;
    u32 offph = (offp - 64u) & 31u;
    u32 psub = plo ? (u32)__popcll(pa & ((1ull << (offp & 63u)) - 1ull))
                   : (u32)__popcll(pa) + (u32)__popc(PE.z & ((1u << offph) - 1u));
    int slot = (int)(PE.w + psub);
    __builtin_assume(slot >= 0);
    bool multi = (mword >> (pk & 63)) & 1ull;

    u32 tv = trans16(acc);
    u32 packed = tv | (((u32)__shfl_down((int)tv, 1)) << 16);  // pair (f, f+1)
    if ((f & 1) == 0) {
        u32* addr = pooled + (size_t)slot * 16 + (f >> 1);
        if (!multi) {
            *addr = packed;                            // ~99%: plain store
        } else {
            u32 oldv = *addr;
            while (true) {
                u32 lo2 = max(oldv & 0xFFFFu, packed & 0xFFFFu);
                u32 hi2 = max(oldv >> 16, packed >> 16);
                u32 mx = lo2 | (hi2 << 16);
                if (mx == oldv) break;
                u32 prev = atomicCAS(addr, oldv, mx);
                if (prev == oldv) break;
                oldv = prev;
            }
        }
    }
}

// K3: half-wave per query point: 27-tap conv (32->32) + output --------------
__global__ __launch_bounds__(TPB, 8)
void query_kernel(const int4* __restrict__ qc,
                  const float* __restrict__ pts,      // stride 5
                  const float* __restrict__ Wc,       // [27][32][32]
                  int m,
                  const uint4* __restrict__ pool_ent,
                  const u16* __restrict__ pooled16,
                  float* __restrict__ out) {
    int p = (blockIdx.x * blockDim.x + threadIdx.x) >> 5;
    if (p >= m) return;
    int lane = threadIdx.x & 63;
    int hb32 = lane & 32;
    int f = lane & 31;

    int4 c = qc[p];                                    // (b,x,y,z)
    int qk = ((c.x * 256 + c.y) * 256 + c.z) * 256 + c.w;
    __builtin_assume(qk >= 65793 && qk < (1 << 25));   // b<2, x/y/z in [1,251)

    int slotL = -1;
    if (f < 27) {
        int t1 = f / 9, rem = f - t1 * 9, t2 = rem / 3, t3 = rem - t2 * 3;
        int nk = qk + (t1 - 1) * 65536 + (t2 - 1) * 256 + (t3 - 1);
        __builtin_assume(nk >= 0 && nk < (1 << 25));
        u32 e = div3((u32)nk >> 5);
        u32 off = (u32)nk - e * 96u;
        uint4 E = pool_ent[e];                         // ONE 16B load (5.6MB, L2)
        u64 a = ((u64)E.y << 32) | E.x;
        bool lo = off < 64u;
        u32 offh = (off - 64u) & 31u;
        u32 bitv = lo ? (u32)((a >> (off & 63u)) & 1ull)
                      : ((E.z >> offh) & 1u);
        if (bitv) {
            u32 sub = lo ? (u32)__popcll(a & ((1ull << (off & 63u)) - 1ull))
                         : (u32)__popcll(a) + (u32)__popc(E.z & ((1u << offh) - 1u));
            slotL = (int)(E.w + sub);
        }
    }
    unsigned long long bal = __ballot(slotL >= 0);
    u32 mymask = (u32)(bal >> hb32);

    float acc = 0.f;
    while (mymask) {
        int b = __ffs(mymask) - 1;                     // tap index
        mymask &= mymask - 1;
        int slot = __shfl(slotL, hb32 + b);
        __builtin_assume(slot >= 0 && slot < (1 << 20));
        float pv = detrans16(pooled16[(size_t)slot * 32 + f]);  // 64B row
        const float* W = Wc + b * 1024 + f;            // W[b][k][f], k-major
        // 32 constant-offset ds_swizzle broadcasts (lane k of each half),
        // no address VGPRs, coalesced 128B W lines:
        kfma(pv, W, acc, std::make_integer_sequence<int, 32>{});
    }

    // paired float2 stores: 16 store lane-requests instead of 32
    float acc2 = __shfl_down(acc, 1);
    if ((f & 1) == 0) {
        float2 st; st.x = acc; st.y = acc2;
        *(float2*)(out + (size_t)p * 36 + 4 + f) = st;
    }
    if (f < 4) out[(size_t)p * 36 + f] = pts[p * 5 + f];  // head
}

// ---------------------------------------------------------------------------
extern "C" void kernel_launch(void* const* d_in, const int* in_sizes, int n_in,
                              void* d_out, int out_size, void* d_ws, size_t ws_size,
                              hipStream_t stream) {
    const float* hfeat   = (const float*)d_in[0];   // [n,1]
    const float* pts     = (const float*)d_in[1];   // [m,5]
    const float* Wbb     = (const float*)d_in[2];   // [27,1,32]
    const float* Wconv   = (const float*)d_in[3];   // [27,32,32]
    const int4*  hcoords = (const int4*)d_in[4];    // [n,4] sorted by packed key
    const int*   hbatch  = (const int*)d_in[5];     // [n]
    const int4*  qcoords = (const int4*)d_in[6];    // [m,4]
    int n = in_sizes[0];
    int m = in_sizes[1] / 5;

    const int NW_H = 1 << 22;                       // 2^28 bits / 64
    const int NW_P = 1 << 19;                       // 2^25 bits / 64
    const size_t EH_ALLOC = (size_t)GB_H2 * TPB * 2;   // 2,796,544 entries
    const size_t EP_ALLOC = (size_t)GB_P2 * TPB * 2;   //   349,696 entries

    // layout: [hist_bm | pool_bm | multi_bm | st] zeroed; rest not zeroed
    char* w = (char*)d_ws;
    char* zbase = w;
    u64* hist_bm      = (u64*)w;       w += (size_t)NW_H * 8;
    u64* pool_bm      = (u64*)w;       w += (size_t)NW_P * 8;
    u64* multi_bm     = (u64*)w;       w += (size_t)NW_P * 8;
    u64* st           = (u64*)w;       w += (size_t)NBLK_SCAN * 8;
    size_t zbytes = (size_t)(w - zbase);
    u32* pooled       = (u32*)w;       w += (size_t)n * 64;      // 16 u32/slot
    uint4* hist_ent   = (uint4*)w;     w += EH_ALLOC * 16;
    uint4* pool_ent   = (uint4*)w;     w += EP_ALLOC * 16;
    int2* kp          = (int2*)w;      w += (size_t)n * 8;

    (void)hipMemsetAsync(zbase, 0x00, zbytes, stream);

    int gb_n   = (n + TPB - 1) / TPB;
    int gb_n32 = (int)(((long long)n * 32 + TPB - 1) / TPB);
    int gb_m32 = (int)(((long long)m * 32 + TPB - 1) / TPB);

    build_bitmaps_kernel<<<gb_n, TPB, 0, stream>>>(hcoords, hbatch, n,
                                                   hist_bm, pool_bm, multi_bm, kp);
    scan_fused_kernel<<<NBLK_SCAN, TPB, 0, stream>>>(hist_bm, pool_bm,
                                                     hist_ent, pool_ent,
                                                     multi_bm, pooled, st);
    bb_pool_kernel<<<gb_n32, TPB, 0, stream>>>(kp, hfeat, Wbb, n,
                                               hist_ent, pool_ent,
                                               multi_bm, pooled);
    query_kernel<<<gb_m32, TPB, 0, stream>>>(qcoords, pts, Wconv, m,
                                             pool_ent,
                                             (const u16*)pooled, (float*)d_out);
}

// Round 13
// 253.929 us; speedup vs baseline: 1.0746x; 1.0746x over previous
//
#include <hip/hip_runtime.h>
#include <stdint.h>
#include <utility>

// ---------------------------------------------------------------------------
// SparseResUQueryNet: bitmap+rank sparse conv -> time max-pool -> sparse conv
//
// Round-21 = round-19 verbatim (verified 256.4us) — reversion after r20's
// fused-entry falsifier fired (requests halved, FETCH -6MB, yet bb_pool +5us
// from extraction VALU; scan +10us from 50MB entry writes).
// FALSIFICATION LEDGER (what this kernel's shape is provably optimal against):
//   - wave-schedule changes: r9/r10 (9-lane probe, VGPR->occupancy loss),
//     r12 (2-pt pipeline, TLP loss) — three reversions.
//   - probe-request reduction at iso-VGPR: r20 (96-key fused entries) — lost
//     to extraction VALU + entry-write traffic. Probes are LATENCY-bound.
//   - chain-lengthening byte/VALU trades: r18 (KDELTA LUT, two-level rank).
//   - query sorting: r7 (cost > gain).
// KEPT WINS: kp key-packing (r19), wave-parallel decoupled-lookback
// single-pass scan (r17), __builtin_assume saddr hints (r16), ds_swizzle
// k-broadcast (r15), scan fusion + fused zero_multi (r15/17), XCD-chunked
// swizzle in bb_pool (r13), float2 stores + memset cut (r11), 27-lane
// parallel bm+rank probe, half-wave per point, VGPR<=32.
// ---------------------------------------------------------------------------

#define TPB 256
#define SCAN_WPT 8
#define GB_H 2048           // hist scan blocks  (NW_H / (TPB*SCAN_WPT))
#define GB_P 256            // pool scan blocks  (NW_P / (TPB*SCAN_WPT))
#define NBLK_SCAN (GB_H + GB_P)
typedef unsigned long long u64;
typedef unsigned int u32;
typedef unsigned short u16;

#define FLAG_AGG (1ull << 62)
#define FLAG_PRE (2ull << 62)
#define FLAG_MSK (3ull << 62)

// f32 -> RNE bf16 -> monotone u16 (order-preserving; 0 is below all reals)
__device__ __forceinline__ u32 trans16(float x) {
    u32 b = __float_as_uint(x);
    u32 bf = (b + 0x7FFFu + ((b >> 16) & 1u)) >> 16;
    return ((bf & 0x8000u) ? (~bf) : (bf | 0x8000u)) & 0xFFFFu;
}
__device__ __forceinline__ float detrans16(u32 u) {
    u32 orig = (u & 0x8000u) ? (u & 0x7FFFu) : ((~u) & 0xFFFFu);
    return __uint_as_float(orig << 16);
}

// broadcast lane K (within each 32-lane half) of pv, FMA against W[K*32] ----
template <int... Ks>
__device__ __forceinline__ void kfma(float pv, const float* __restrict__ W,
                                     float& acc,
                                     std::integer_sequence<int, Ks...>) {
    ((acc = fmaf(__uint_as_float((u32)__builtin_amdgcn_ds_swizzle(
                     (int)__float_as_uint(pv), (Ks << 5))),
                 W[Ks * 32], acc)),
     ...);
}

// K1: set existence bits; second pool contributor marks multi; pack keys -----
__global__ void build_bitmaps_kernel(const int4* __restrict__ hc,
                                     const int* __restrict__ hb,
                                     int n,
                                     u64* __restrict__ hist_bm,
                                     u64* __restrict__ pool_bm,
                                     u64* __restrict__ multi_bm,
                                     int2* __restrict__ kp) {
    int j = blockIdx.x * blockDim.x + threadIdx.x;
    if (j >= n) return;
    int4 c = hc[j];                                   // (t,x,y,z)
    int key = ((c.x * 256 + c.y) * 256 + c.z) * 256 + c.w;
    atomicOr(&hist_bm[key >> 6], 1ull << (key & 63));
    int pk = ((hb[j] * 256 + c.y) * 256 + c.z) * 256 + c.w;
    kp[j] = make_int2(key, pk);                       // keys for bb_pool
    u64 bit = 1ull << (pk & 63);
    u64 old = atomicOr(&pool_bm[pk >> 6], bit);
    if (old & bit) atomicOr(&multi_bm[pk >> 6], bit); // >=2 contributors
}

// single-pass scan: local popcount scan + WAVE-PARALLEL decoupled lookback +
// rank write; pool branch also zeroes the CAS-max pooled rows ---------------
__global__ void scan_fused_kernel(const u64* __restrict__ hist_bm,
                                  const u64* __restrict__ pool_bm,
                                  u32* __restrict__ hist_rank,
                                  u32* __restrict__ pool_rank,
                                  const u64* __restrict__ multi_bm,
                                  u32* __restrict__ pooled,
                                  u64* __restrict__ st) {  // [NBLK_SCAN] zeroed
    __shared__ u32 s[TPB];
    __shared__ u32 sbase;
    int t = threadIdx.x;
    bool isPool = blockIdx.x >= GB_H;
    const u64* bm = isPool ? pool_bm : hist_bm;
    u32* rank = isPool ? pool_rank : hist_rank;
    int blk = isPool ? (blockIdx.x - GB_H) : blockIdx.x;
    size_t base = ((size_t)blk * TPB + t) * SCAN_WPT;
    u32 pc[SCAN_WPT]; u32 acc = 0;
#pragma unroll
    for (int i = 0; i < SCAN_WPT; i++) { pc[i] = __popcll(bm[base + i]); acc += pc[i]; }
    s[t] = acc; __syncthreads();
    for (int off = 1; off < TPB; off <<= 1) {          // inclusive Hillis-Steele
        u32 x = (t >= off) ? s[t - off] : 0;
        __syncthreads();
        s[t] += x;
        __syncthreads();
    }
    u32 wave_excl = s[t] - acc;                        // block-local exclusive
    u32 blocksum = s[TPB - 1];                         // block aggregate

    int segStart = isPool ? GB_H : 0;
    if (t < 64) {                                      // first wave does lookback
        if (blockIdx.x == segStart) {                  // segment head
            if (t == 0) {
                atomicExch(&st[blockIdx.x], FLAG_PRE | (u64)blocksum);
                sbase = 0;
            }
        } else {
            if (t == 0) atomicExch(&st[blockIdx.x], FLAG_AGG | (u64)blocksum);
            u64 run = 0;
            int end = blockIdx.x;                      // window (end-64, end]
            while (true) {
                int i = end - 1 - t;                   // lane 0 = closest pred
                u64 v = (i >= segStart) ? atomicAdd(&st[i], 0ull)
                                        : FLAG_AGG;    // synthetic AGG(0)
                u64 fl = v & FLAG_MSK;
                u64 pre_mask   = __ballot(fl == FLAG_PRE);
                u64 unpub_mask = __ballot(fl == 0ull);
                int first_pre   = pre_mask   ? (__ffsll((long long)pre_mask) - 1)   : 64;
                int first_unpub = unpub_mask ? (__ffsll((long long)unpub_mask) - 1) : 64;
                if (first_pre < first_unpub) {         // consumable prefix found
                    u32 contrib = (t <= first_pre) ? (u32)(v & 0xFFFFFFFFull) : 0u;
#pragma unroll
                    for (int off = 1; off < 64; off <<= 1)
                        contrib += (u32)__shfl_xor((int)contrib, off);
                    run += contrib;
                    break;
                } else if (first_unpub == 64) {        // all AGG: consume window
                    u32 contrib = (u32)(v & 0xFFFFFFFFull);
#pragma unroll
                    for (int off = 1; off < 64; off <<= 1)
                        contrib += (u32)__shfl_xor((int)contrib, off);
                    run += contrib;
                    end -= 64;
                }                                      // else: re-poll window
            }
            if (t == 0) {
                atomicExch(&st[blockIdx.x], FLAG_PRE | (run + (u64)blocksum));
                sbase = (u32)run;
            }
        }
    }
    __syncthreads();

    u32 run = sbase + wave_excl;
    u32 run0 = run;
#pragma unroll
    for (int i = 0; i < SCAN_WPT; i++) { rank[base + i] = run; run += pc[i]; }
    if (isPool) {                                      // fused zero_multi
        u32 r2 = run0;
#pragma unroll
        for (int i = 0; i < SCAN_WPT; i++) {
            u64 mw = multi_bm[base + i];
            if (mw) {
                u64 pw = bm[base + i];                 // L1-hot reload
                while (mw) {
                    int b = __ffsll((long long)mw) - 1;
                    mw &= mw - 1;
                    u32 slot = r2 + (u32)__popcll(pw & ((1ull << b) - 1ull));
                    u32* row = pooled + (size_t)slot * 16;
#pragma unroll
                    for (int w2 = 0; w2 < 16; w2++) row[w2] = 0u;
                }
            }
            r2 += pc[i];
        }
    }
}

// K2: half-wave per voxel: 27-tap conv (1->32) + packed pooled write --------
__global__ __launch_bounds__(TPB, 8)
void bb_pool_kernel(const int2* __restrict__ kp,      // packed (key, pk)
                    const float* __restrict__ hf,
                    const float* __restrict__ Wbb,   // [27*32]
                    int n,
                    const u64* __restrict__ hist_bm,
                    const u32* __restrict__ hist_rank,
                    const u64* __restrict__ pool_bm,
                    const u32* __restrict__ pool_rank,
                    const u64* __restrict__ multi_bm,
                    u32* __restrict__ pooled) {
    // XCD-chunked bijective swizzle (r13, verified): contiguous key range per
    // XCD so its private L2 holds 1/8 of hist_bm/rank.
    int nwg = gridDim.x;
    int q = nwg >> 3, r = nwg & 7;
    int xcd = blockIdx.x & 7, idx = blockIdx.x >> 3;
    int swz = (xcd < r ? xcd * (q + 1) : r * (q + 1) + (xcd - r) * q) + idx;

    int p = (swz * TPB + threadIdx.x) >> 5;            // voxel index
    if (p >= n) return;
    int lane = threadIdx.x & 63;
    int hb32 = lane & 32;                              // half base within wave
    int f = lane & 31;                                 // feature / tap lane

    int2 k2 = kp[p];                                   // one 8B broadcast load
    int key = k2.x, pk = k2.y;
    __builtin_assume(key >= 65793 && key < (1 << 28)); // t<16, x/y/z in [1,251)
    __builtin_assume(pk >= 65793 && pk < (1 << 25));   // b<2

    // pool-side loads issued early (independent of probe chain)
    u64 pword = pool_bm[pk >> 6];
    u32 prank = pool_rank[pk >> 6];
    u64 mword = multi_bm[pk >> 6];

    float fv = 0.f;
    bool hit = false;
    if (f < 27) {
        int t1 = f / 9, rem = f - t1 * 9, t2 = rem / 3, t3 = rem - t2 * 3;
        int nk = key + (t1 - 1) * 65536 + (t2 - 1) * 256 + (t3 - 1);
        __builtin_assume(nk >= 0 && nk < (1 << 28));
        u64 word = hist_bm[nk >> 6];                   // parallel independent
        u32 rk   = hist_rank[nk >> 6];                 // loads (overlapped)
        if ((word >> (nk & 63)) & 1ull) {
            u32 r2 = rk + (u32)__popcll(word & ((1ull << (nk & 63)) - 1ull));
            __builtin_assume(r2 < (1u << 20));         // rank < n < 2^20
            fv = hf[r2];                               // rank == row index j
            hit = true;
        }
    }
    unsigned long long bal = __ballot(hit);
    u32 mymask = (u32)(bal >> hb32);                   // this half's hit taps

    float acc = 0.f;
    while (mymask) {
        int b = __ffs(mymask) - 1;
        mymask &= mymask - 1;
        float fb = __shfl(fv, hb32 + b);               // broadcast neighbor feat
        acc = fmaf(fb, Wbb[b * 32 + f], acc);          // L1-hot 3.4KB table
    }

    int bit = pk & 63;
    int slot = (int)(prank + (u32)__popcll(pword & ((1ull << bit) - 1ull)));
    __builtin_assume(slot >= 0);
    bool multi = (mword >> bit) & 1ull;

    u32 tv = trans16(acc);
    u32 packed = tv | (((u32)__shfl_down((int)tv, 1)) << 16);  // pair (f, f+1)
    if ((f & 1) == 0) {
        u32* addr = pooled + (size_t)slot * 16 + (f >> 1);
        if (!multi) {
            *addr = packed;                            // ~99%: plain store
        } else {
            u32 oldv = *addr;
            while (true) {
                u32 lo = max(oldv & 0xFFFFu, packed & 0xFFFFu);
                u32 hi = max(oldv >> 16, packed >> 16);
                u32 mx = lo | (hi << 16);
                if (mx == oldv) break;
                u32 prev = atomicCAS(addr, oldv, mx);
                if (prev == oldv) break;
                oldv = prev;
            }
        }
    }
}

// K3: half-wave per query point: 27-tap conv (32->32) + output --------------
__global__ __launch_bounds__(TPB, 8)
void query_kernel(const int4* __restrict__ qc,
                  const float* __restrict__ pts,      // stride 5
                  const float* __restrict__ Wc,       // [27][32][32]
                  int m,
                  const u64* __restrict__ pool_bm,
                  const u32* __restrict__ pool_rank,
                  const u16* __restrict__ pooled16,
                  float* __restrict__ out) {
    int p = (blockIdx.x * blockDim.x + threadIdx.x) >> 5;
    if (p >= m) return;
    int lane = threadIdx.x & 63;
    int hb32 = lane & 32;
    int f = lane & 31;

    int4 c = qc[p];                                    // (b,x,y,z)
    int qk = ((c.x * 256 + c.y) * 256 + c.z) * 256 + c.w;
    __builtin_assume(qk >= 65793 && qk < (1 << 25));   // b<2, x/y/z in [1,251)

    int slotL = -1;
    if (f < 27) {
        int t1 = f / 9, rem = f - t1 * 9, t2 = rem / 3, t3 = rem - t2 * 3;
        int nk = qk + (t1 - 1) * 65536 + (t2 - 1) * 256 + (t3 - 1);
        __builtin_assume(nk >= 0 && nk < (1 << 25));
        u64 word = pool_bm[nk >> 6];                   // 4MB, mostly L2
        u32 rk   = pool_rank[nk >> 6];                 // 2MB, parallel load
        if ((word >> (nk & 63)) & 1ull)
            slotL = (int)(rk + (u32)__popcll(word & ((1ull << (nk & 63)) - 1ull)));
    }
    unsigned long long bal = __ballot(slotL >= 0);
    u32 mymask = (u32)(bal >> hb32);

    float acc = 0.f;
    while (mymask) {
        int b = __ffs(mymask) - 1;                     // tap index
        mymask &= mymask - 1;
        int slot = __shfl(slotL, hb32 + b);
        __builtin_assume(slot >= 0 && slot < (1 << 20));
        float pv = detrans16(pooled16[(size_t)slot * 32 + f]);  // 64B row
        const float* W = Wc + b * 1024 + f;            // W[b][k][f], k-major
        // 32 constant-offset ds_swizzle broadcasts (lane k of each half),
        // no address VGPRs, coalesced 128B W lines:
        kfma(pv, W, acc, std::make_integer_sequence<int, 32>{});
    }

    // paired float2 stores: 16 store lane-requests instead of 32
    float acc2 = __shfl_down(acc, 1);
    if ((f & 1) == 0) {
        float2 st; st.x = acc; st.y = acc2;
        *(float2*)(out + (size_t)p * 36 + 4 + f) = st;
    }
    if (f < 4) out[(size_t)p * 36 + f] = pts[p * 5 + f];  // head
}

// ---------------------------------------------------------------------------
extern "C" void kernel_launch(void* const* d_in, const int* in_sizes, int n_in,
                              void* d_out, int out_size, void* d_ws, size_t ws_size,
                              hipStream_t stream) {
    const float* hfeat   = (const float*)d_in[0];   // [n,1]
    const float* pts     = (const float*)d_in[1];   // [m,5]
    const float* Wbb     = (const float*)d_in[2];   // [27,1,32]
    const float* Wconv   = (const float*)d_in[3];   // [27,32,32]
    const int4*  hcoords = (const int4*)d_in[4];    // [n,4] sorted by packed key
    const int*   hbatch  = (const int*)d_in[5];     // [n]
    const int4*  qcoords = (const int4*)d_in[6];    // [m,4]
    int n = in_sizes[0];
    int m = in_sizes[1] / 5;

    const int NW_H = 1 << 22;                       // 2^28 bits / 64
    const int NW_P = 1 << 19;                       // 2^25 bits / 64

    // layout: [hist_bm | pool_bm | multi_bm | st] zeroed; pooled/kp NOT zeroed
    char* w = (char*)d_ws;
    char* zbase = w;
    u64* hist_bm      = (u64*)w;       w += (size_t)NW_H * 8;
    u64* pool_bm      = (u64*)w;       w += (size_t)NW_P * 8;
    u64* multi_bm     = (u64*)w;       w += (size_t)NW_P * 8;
    u64* st           = (u64*)w;       w += (size_t)NBLK_SCAN * 8;
    size_t zbytes = (size_t)(w - zbase);
    u32* pooled       = (u32*)w;       w += (size_t)n * 64;      // 16 u32/slot
    u32* hist_rank    = (u32*)w;       w += (size_t)NW_H * 4;
    u32* pool_rank    = (u32*)w;       w += (size_t)NW_P * 4;
    int2* kp          = (int2*)w;      w += (size_t)n * 8;

    (void)hipMemsetAsync(zbase, 0x00, zbytes, stream);

    int gb_n   = (n + TPB - 1) / TPB;
    int gb_n32 = (int)(((long long)n * 32 + TPB - 1) / TPB);
    int gb_m32 = (int)(((long long)m * 32 + TPB - 1) / TPB);

    build_bitmaps_kernel<<<gb_n, TPB, 0, stream>>>(hcoords, hbatch, n,
                                                   hist_bm, pool_bm, multi_bm, kp);
    scan_fused_kernel<<<NBLK_SCAN, TPB, 0, stream>>>(hist_bm, pool_bm,
                                                     hist_rank, pool_rank,
                                                     multi_bm, pooled, st);
    bb_pool_kernel<<<gb_n32, TPB, 0, stream>>>(kp, hfeat, Wbb, n,
                                               hist_bm, hist_rank,
                                               pool_bm, pool_rank, multi_bm, pooled);
    query_kernel<<<gb_m32, TPB, 0, stream>>>(qcoords, pts, Wconv, m,
                                             pool_bm, pool_rank,
                                             (const u16*)pooled, (float*)d_out);
}